// Round 1
// baseline (873.943 us; speedup 1.0000x reference)
//
#include <hip/hip_runtime.h>
#include <hip/hip_bf16.h>

// ---------------------------------------------------------------------------
// ramsey_NN: node MLP (3 layers, train-mode BN) + all-pairs edge head.
// N=2048, F=64, H=128, C=2.  E = N(N-1)/2 = 2096128.
//
// Structure:
//   K_w5t : W5 (fp32 [F][H]) -> bf16, stored in MFMA-B fragment-physical order
//   K_l1  : act1 = lrelu(nf @ W1 + b1), channel sums/sumsq -> stat1
//   K_l2  : act2 = lrelu(BN1(act1) @ W2 + b2), sums/sumsq -> stat2
//   K_l3  : h    = BN2(act2) @ W3 + b3 + nf  -> hb (bf16 [N][F])
//   edge_pass(pass2=0): triangle-tiled MFMA GEMM, accumulate S,Q of
//                       lrelu(z+b5) per channel (BN stats over E edges)
//   K_mid : fold BN+softmax into w6d[128], b6d  (p0 = sigmoid(sum a*w6d + b6d))
//   edge_pass(pass2=1): recompute z, reduce to p, write probs[i][j] & [j][i]
//   K_diag: zero the diagonal
// ---------------------------------------------------------------------------

typedef short short8 __attribute__((ext_vector_type(8)));   // 8 x bf16 (4 VGPR)
typedef float floatx4 __attribute__((ext_vector_type(4)));  // MFMA C/D

#define NN 2048
#define FF 64
#define HH 128
#define EPSV 1e-5f
#define SLOPE 0.01f

__device__ __forceinline__ float bf2f(short s) {
    return __uint_as_float(((unsigned)(unsigned short)s) << 16);
}
__device__ __forceinline__ short f2bf(float f) {   // round-to-nearest-even
    unsigned u = __float_as_uint(f);
    unsigned r = (u + 0x7FFFu + ((u >> 16) & 1u)) >> 16;
    return (short)r;
}
__device__ __forceinline__ float lrelu(float x) { return fmaxf(x, SLOPE * x); }

// B-fragment physical index for bf16 16x16x32: frag (nt=h>>4, ks=f>>5),
// lane = quad*16+col with quad=(f>>3)&3, col=h&15, element e=f&7.
__device__ __forceinline__ int physB(int h, int f) {
    return ((((h >> 4) * 2 + (f >> 5)) * 64 + ((f >> 3) & 3) * 16 + (h & 15)) * 8) + (f & 7);
}

// ---------------- W5 -> bf16 fragment-physical -------------------------------
__global__ __launch_bounds__(256) void k_w5t(const float* __restrict__ W5,
                                             short* __restrict__ w5t) {
    int idx = blockIdx.x * 256 + threadIdx.x;      // grid 32 -> 8192
    int h = idx >> 6, f = idx & 63;
    w5t[physB(h, f)] = f2bf(W5[f * HH + h]);
}

// ---------------- node layer 1 ----------------------------------------------
__global__ __launch_bounds__(256) void k_l1(const float* __restrict__ nf,
                                            const float* __restrict__ W1,
                                            const float* __restrict__ b1,
                                            float* __restrict__ act1,
                                            float* __restrict__ stat1) {
    __shared__ float xl[64 * 64];
    __shared__ float sS[128], sQ[128];
    int t = threadIdx.x, n0 = blockIdx.x * 64;
    if (t < 128) { sS[t] = 0.f; sQ[t] = 0.f; }
    for (int k = 0; k < 16; ++k) {
        int e = t + 256 * k;
        xl[e] = nf[(size_t)n0 * 64 + e];
    }
    __syncthreads();
    int nl = t >> 2, hq = t & 3, ho0 = hq * 32;
    float acc[32];
    for (int k = 0; k < 32; ++k) acc[k] = b1[ho0 + k];
    for (int f = 0; f < 64; ++f) {
        float r = xl[nl * 64 + f];
        const float* wr = W1 + f * HH + ho0;
        for (int k = 0; k < 32; ++k) acc[k] += r * wr[k];
    }
    for (int k = 0; k < 32; ++k) {
        float a = lrelu(acc[k]);
        act1[(size_t)(n0 + nl) * HH + ho0 + k] = a;
        atomicAdd(&sS[ho0 + k], a);
        atomicAdd(&sQ[ho0 + k], a * a);
    }
    __syncthreads();
    if (t < 128) atomicAdd(&stat1[t], sS[t]);
    else atomicAdd(&stat1[t], sQ[t - 128]);
}

// ---------------- node layer 2 ----------------------------------------------
__global__ __launch_bounds__(256) void k_l2(const float* __restrict__ act1,
                                            const float* __restrict__ stat1,
                                            const float* __restrict__ g1,
                                            const float* __restrict__ be1,
                                            const float* __restrict__ W2,
                                            const float* __restrict__ b2,
                                            float* __restrict__ act2,
                                            float* __restrict__ stat2) {
    __shared__ float a1n[64 * 128];
    __shared__ float sS[128], sQ[128];
    int t = threadIdx.x, n0 = blockIdx.x * 64;
    if (t < 128) { sS[t] = 0.f; sQ[t] = 0.f; }
    for (int k = 0; k < 32; ++k) {
        int e = t + 256 * k;
        int nl = e >> 7, h = e & 127;
        float m = stat1[h] * (1.f / 2048.f);
        float v = stat1[128 + h] * (1.f / 2048.f) - m * m;
        float sc = rsqrtf(v + EPSV);
        float a = act1[(size_t)(n0 + nl) * HH + h];
        a1n[e] = (a - m) * sc * g1[h] + be1[h];
    }
    __syncthreads();
    int nl = t >> 2, hq = t & 3, ho0 = hq * 32;
    float acc[32];
    for (int k = 0; k < 32; ++k) acc[k] = b2[ho0 + k];
    for (int hi = 0; hi < 128; ++hi) {
        float r = a1n[nl * 128 + hi];
        const float* wr = W2 + hi * HH + ho0;
        for (int k = 0; k < 32; ++k) acc[k] += r * wr[k];
    }
    for (int k = 0; k < 32; ++k) {
        float a = lrelu(acc[k]);
        act2[(size_t)(n0 + nl) * HH + ho0 + k] = a;
        atomicAdd(&sS[ho0 + k], a);
        atomicAdd(&sQ[ho0 + k], a * a);
    }
    __syncthreads();
    if (t < 128) atomicAdd(&stat2[t], sS[t]);
    else atomicAdd(&stat2[t], sQ[t - 128]);
}

// ---------------- node layer 3 + residual -> hb (bf16) -----------------------
__global__ __launch_bounds__(256) void k_l3(const float* __restrict__ act2,
                                            const float* __restrict__ stat2,
                                            const float* __restrict__ g2,
                                            const float* __restrict__ be2,
                                            const float* __restrict__ W3,
                                            const float* __restrict__ b3,
                                            const float* __restrict__ nf,
                                            short* __restrict__ hb) {
    __shared__ float a2n[64 * 128];
    int t = threadIdx.x, n0 = blockIdx.x * 64;
    for (int k = 0; k < 32; ++k) {
        int e = t + 256 * k;
        int nl = e >> 7, h = e & 127;
        float m = stat2[h] * (1.f / 2048.f);
        float v = stat2[128 + h] * (1.f / 2048.f) - m * m;
        float sc = rsqrtf(v + EPSV);
        float a = act2[(size_t)(n0 + nl) * HH + h];
        a2n[e] = (a - m) * sc * g2[h] + be2[h];
    }
    __syncthreads();
    int nl = t >> 2, fq = t & 3, f0 = fq * 16;
    float acc[16];
    for (int k = 0; k < 16; ++k) acc[k] = 0.f;
    for (int hi = 0; hi < 128; ++hi) {
        float r = a2n[nl * 128 + hi];
        const float* wr = W3 + hi * FF + f0;
        for (int k = 0; k < 16; ++k) acc[k] += r * wr[k];
    }
    for (int k = 0; k < 16; ++k) {
        float val = acc[k] + b3[f0 + k] + nf[(size_t)(n0 + nl) * FF + f0 + k];
        hb[(size_t)(n0 + nl) * FF + f0 + k] = f2bf(val);
    }
}

// ---------------- BN+softmax fold -------------------------------------------
__global__ void k_mid(const float* __restrict__ SQe, const float* __restrict__ W6,
                      const float* __restrict__ b6, const float* __restrict__ g5,
                      const float* __restrict__ be5, float* __restrict__ w6d,
                      float* __restrict__ b6d) {
    __shared__ float part[128];
    int h = threadIdx.x;
    const float Ef = 2096128.f;
    float m = SQe[h] / Ef;
    float v = SQe[128 + h] / Ef - m * m;
    float s = rsqrtf(v + EPSV);
    float dW = W6[h * 2] - W6[h * 2 + 1];
    float sg = s * g5[h];
    w6d[h] = sg * dW;
    part[h] = (be5[h] - m * sg) * dW;
    __syncthreads();
    if (h == 0) {
        float acc = b6[0] - b6[1];
        for (int k = 0; k < 128; ++k) acc += part[k];
        b6d[0] = acc;
    }
}

// ---------------- diagonal zeros --------------------------------------------
__global__ __launch_bounds__(256) void k_diag(float* __restrict__ out) {
    int i = blockIdx.x * 256 + threadIdx.x;   // grid 8 -> 2048
    size_t base = ((size_t)i * NN + i) * 2;
    out[base] = 0.f;
    out[base + 1] = 0.f;
}

// ---------------- the big one: triangle edge GEMM ----------------------------
// Tile: 16 i's (blockIdx.y) x 128 j's (blockIdx.x). 4 waves, each owns 32 j's.
// z[j,h] via mfma_f32_16x16x32_bf16: A[m=j][k=f] from hb, B_i[k=f][n=h] built
// in LDS (fragment-physical) as h_i[f]*W5[f,h].
// C/D layout (verified m89/m91): col=lane&15 (=h), row=quad*4+reg (=j).
// A layout: A[m=lane&15][k=quad*8+e]; B: B[k=quad*8+e][n=lane&15].
__global__ __launch_bounds__(256) void edge_pass(
    const short* __restrict__ hb, const short* __restrict__ w5t,
    const float* __restrict__ b5, const float* __restrict__ w6d,
    const float* __restrict__ b6dp, float* __restrict__ SQe,
    float* __restrict__ out, int pass2)
{
    int jt = blockIdx.x;   // 0..15
    int ig = blockIdx.y;   // 0..127
    if (jt * 128 + 127 <= ig * 16) return;   // no j > i in this tile

    __shared__ alignas(16) short sW5t[128 * 64];  // fragment-physical
    __shared__ alignas(16) short sB[128 * 64];    // fragment-physical B_i
    __shared__ alignas(16) short sHi[16 * 64];    // h_i rows (row-major)
    __shared__ float sD[16][128];                 // pass2: p per (i,j)
    __shared__ float sS[128], sQ[128];            // pass1 partial stats

    int t = threadIdx.x;
    int lane = t & 63, w = t >> 6;
    int quad = lane >> 4, col = lane & 15;

    {   // stage W5t (16 KB) + h_i rows (2 KB)
        const int4* s1 = (const int4*)w5t;
        int4* d1 = (int4*)sW5t;
        for (int k = 0; k < 4; ++k) d1[t + 256 * k] = s1[t + 256 * k];
        if (t < 128)
            ((int4*)sHi)[t] = ((const int4*)(hb + (size_t)ig * 1024))[t];
        if (!pass2 && t < 128) { sS[t] = 0.f; sQ[t] = 0.f; }
    }

    // A fragments: 2 m-tiles x 2 k-steps, straight from global hb
    short8 afr[2][2];
    int j_base = jt * 128 + w * 32;
    for (int mt = 0; mt < 2; ++mt)
        for (int ks = 0; ks < 2; ++ks) {
            int j = j_base + mt * 16 + col;
            afr[mt][ks] = *(const short8*)(hb + (size_t)j * 64 + ks * 32 + quad * 8);
        }

    float b5l[8], w6l[8];
    for (int nt = 0; nt < 8; ++nt) {
        b5l[nt] = b5[nt * 16 + col];
        w6l[nt] = pass2 ? w6d[nt * 16 + col] : 0.f;
    }
    float bb = pass2 ? b6dp[0] : 0.f;
    float S8[8], Q8[8];
    for (int nt = 0; nt < 8; ++nt) { S8[nt] = 0.f; Q8[nt] = 0.f; }

    // build-phase thread mapping: 8 contiguous f per thread, conflict-free
    int th = t >> 3;            // h base (0..31), +32 per c8 step
    int tf = (t & 7) * 8;       // f chunk

    for (int i = 0; i < 16; ++i) {
        int i_glob = ig * 16 + i;
        __syncthreads();
        // build B_i = h_i[f] * W5[f,h] into sB (fragment-physical)
        for (int c8 = 0; c8 < 4; ++c8) {
            int h = th + c8 * 32;
            int base = physB(h, tf);
            short8 wv = *(const short8*)(sW5t + base);
            short8 hv = *(const short8*)(sHi + i * 64 + tf);
            short8 ov;
            for (int e = 0; e < 8; ++e)
                ov[e] = f2bf(bf2f(wv[e]) * bf2f(hv[e]));
            *(short8*)(sB + base) = ov;
        }
        __syncthreads();

        float dp0[4] = {0.f, 0.f, 0.f, 0.f};
        float dp1[4] = {0.f, 0.f, 0.f, 0.f};
        for (int nt = 0; nt < 8; ++nt) {
            short8 bfr0 = *(const short8*)(sB + ((nt * 2 + 0) * 64 + lane) * 8);
            short8 bfr1 = *(const short8*)(sB + ((nt * 2 + 1) * 64 + lane) * 8);
            for (int mt = 0; mt < 2; ++mt) {
                floatx4 c = {0.f, 0.f, 0.f, 0.f};
                c = __builtin_amdgcn_mfma_f32_16x16x32_bf16(afr[mt][0], bfr0, c, 0, 0, 0);
                c = __builtin_amdgcn_mfma_f32_16x16x32_bf16(afr[mt][1], bfr1, c, 0, 0, 0);
                float* dp = mt ? dp1 : dp0;
                for (int r = 0; r < 4; ++r) {
                    int j_glob = j_base + mt * 16 + quad * 4 + r;
                    float z = c[r] + b5l[nt];
                    float a = lrelu(z);
                    if (!pass2) {
                        if (j_glob > i_glob) { S8[nt] += a; Q8[nt] += a * a; }
                    } else {
                        dp[r] += a * w6l[nt];
                    }
                }
            }
        }
        if (pass2) {
            for (int mt = 0; mt < 2; ++mt) {
                float* dp = mt ? dp1 : dp0;
                for (int r = 0; r < 4; ++r) {
                    float v = dp[r];
                    v += __shfl_xor(v, 1);
                    v += __shfl_xor(v, 2);
                    v += __shfl_xor(v, 4);
                    v += __shfl_xor(v, 8);
                    if (col == 0) {
                        float p = 1.f / (1.f + __expf(-(v + bb)));
                        sD[i][w * 32 + mt * 16 + quad * 4 + r] = p;
                    }
                }
            }
        }
    }

    if (!pass2) {
        for (int nt = 0; nt < 8; ++nt) {
            float s = S8[nt], q = Q8[nt];
            s += __shfl_xor(s, 16); s += __shfl_xor(s, 32);
            q += __shfl_xor(q, 16); q += __shfl_xor(q, 32);
            if (quad == 0) {
                atomicAdd(&sS[nt * 16 + col], s);
                atomicAdd(&sQ[nt * 16 + col], q);
            }
        }
        __syncthreads();
        if (t < 128) atomicAdd(&SQe[t], sS[t]);
        else atomicAdd(&SQe[t], sQ[t - 128]);
    } else {
        __syncthreads();
        int ig0 = ig * 16, j0 = jt * 128;
        int jl = t >> 1, cc = t & 1;
        for (int i = 0; i < 16; ++i) {       // direct rows: coalesced
            int i_glob = ig0 + i, j_glob = j0 + jl;
            if (j_glob > i_glob) {
                float p = sD[i][jl];
                out[((size_t)i_glob * NN + j_glob) * 2 + cc] = cc ? 1.f - p : p;
            }
        }
        for (int rep = 0; rep < 16; ++rep) { // mirror: 128B per j row
            int jr = rep * 8 + (t >> 5);
            int inner = t & 31;
            int il = inner >> 1, c2 = inner & 1;
            int j_glob = j0 + jr, i_glob = ig0 + il;
            if (j_glob > i_glob) {
                float p = sD[il][jr];
                out[((size_t)j_glob * NN + i_glob) * 2 + c2] = c2 ? 1.f - p : p;
            }
        }
    }
}

// ---------------------------------------------------------------------------
extern "C" void kernel_launch(void* const* d_in, const int* in_sizes, int n_in,
                              void* d_out, int out_size, void* d_ws, size_t ws_size,
                              hipStream_t stream) {
    const float* nf  = (const float*)d_in[1];   // node_features (d_in[0]=x unused)
    const float* W1  = (const float*)d_in[2];
    const float* b1  = (const float*)d_in[3];
    const float* g1  = (const float*)d_in[4];
    const float* be1 = (const float*)d_in[5];
    const float* W2  = (const float*)d_in[6];
    const float* b2  = (const float*)d_in[7];
    const float* g2  = (const float*)d_in[8];
    const float* be2 = (const float*)d_in[9];
    const float* W3  = (const float*)d_in[10];
    const float* b3  = (const float*)d_in[11];
    const float* W5  = (const float*)d_in[12];
    const float* b5  = (const float*)d_in[13];
    const float* g5  = (const float*)d_in[14];
    const float* be5 = (const float*)d_in[15];
    const float* W6  = (const float*)d_in[16];
    const float* b6  = (const float*)d_in[17];
    float* out = (float*)d_out;

    float* wsf   = (float*)d_ws;
    float* stat1 = wsf;                 // 256
    float* stat2 = wsf + 256;           // 256
    float* SQe   = wsf + 512;           // 256
    float* w6d   = wsf + 768;           // 128
    float* b6dp  = wsf + 896;           // 1 (pad to 1024)
    float* act1  = wsf + 1024;          // 262144
    float* act2  = act1 + 262144;       // 262144
    short* hb    = (short*)(act2 + 262144);   // 131072 bf16
    short* w5t   = hb + 131072;               // 8192 bf16

    // zero the accumulators (ws is poisoned 0xAA before every call)
    hipMemsetAsync(d_ws, 0, 1024 * sizeof(float), stream);

    k_w5t<<<32, 256, 0, stream>>>(W5, w5t);
    k_l1<<<32, 256, 0, stream>>>(nf, W1, b1, act1, stat1);
    k_l2<<<32, 256, 0, stream>>>(act1, stat1, g1, be1, W2, b2, act2, stat2);
    k_l3<<<32, 256, 0, stream>>>(act2, stat2, g2, be2, W3, b3, nf, hb);

    dim3 grid(16, 128);
    edge_pass<<<grid, 256, 0, stream>>>(hb, w5t, b5, w6d, b6dp, SQe, out, 0);
    k_mid<<<1, 128, 0, stream>>>(SQe, W6, b6, g5, be5, w6d, b6dp);
    edge_pass<<<grid, 256, 0, stream>>>(hb, w5t, b5, w6d, b6dp, SQe, out, 1);
    k_diag<<<8, 256, 0, stream>>>(out);
}

// Round 2
// 416.337 us; speedup vs baseline: 2.0991x; 2.0991x over previous
//
#include <hip/hip_runtime.h>
#include <hip/hip_bf16.h>

// ---------------------------------------------------------------------------
// ramsey_NN: node MLP (3 layers, train-mode BN) + all-pairs edge head.
// N=2048, F=64, H=128, C=2.  E = N(N-1)/2 = 2096128.
//
// R2 structure (vs R1: killed per-i LDS build + 32 barriers/block + 8-way
// bank conflicts):
//   k_w5t : W5 -> bf16 in MFMA fragment-physical order
//   k_l1/2/3 : node MLP (widened to 128 blocks)
//   k_bi  : T[i] = diag(h_i) @ W5, bf16, fragment-physical, 32 MB (once)
//   edge_pass(0): barrier-free i-loop; m=j,n=h orientation; stats per h=col
//   k_mid : fold BN+softmax -> w6d[128], b6d
//   edge_pass(1): same loads, operands swapped (m=h,n=j) so per-edge h-sum
//                 is 2 shfl_xor; sigmoid + symmetric write
//   k_diag: zero diagonal
// Fragment identity used: A-phys(m,k) == B-phys(k,n) under m<->n, so the same
// 16B chunks of T / hb serve as A or B depending on pass.
// ---------------------------------------------------------------------------

typedef short short8 __attribute__((ext_vector_type(8)));   // 8 x bf16
typedef float floatx4 __attribute__((ext_vector_type(4)));  // MFMA C/D

#define NN 2048
#define EPSV 1e-5f
#define SLOPE 0.01f

__device__ __forceinline__ float bf2f(short s) {
    return __uint_as_float(((unsigned)(unsigned short)s) << 16);
}
__device__ __forceinline__ short f2bf(float f) {   // RNE
    unsigned u = __float_as_uint(f);
    unsigned r = (u + 0x7FFFu + ((u >> 16) & 1u)) >> 16;
    return (short)r;
}
__device__ __forceinline__ float lrelu(float x) { return fmaxf(x, SLOPE * x); }

// fragment-physical index: chunk = ((h>>4)*2 + f>>5)*64 + ((f>>3)&3)*16 + (h&15)
__device__ __forceinline__ int physB(int h, int f) {
    return ((((h >> 4) * 2 + (f >> 5)) * 64 + ((f >> 3) & 3) * 16 + (h & 15)) * 8) + (f & 7);
}

// ---------------- W5 -> bf16 fragment-physical -------------------------------
__global__ __launch_bounds__(256) void k_w5t(const float* __restrict__ W5,
                                             short* __restrict__ w5t) {
    int idx = blockIdx.x * 256 + threadIdx.x;      // grid 32
    int h = idx >> 6, f = idx & 63;
    w5t[physB(h, f)] = f2bf(W5[f * 128 + h]);
}

// ---------------- node layer 1 (128 blocks x 16 nodes) -----------------------
__global__ __launch_bounds__(256) void k_l1(const float* __restrict__ nf,
                                            const float* __restrict__ W1,
                                            const float* __restrict__ b1,
                                            float* __restrict__ act1,
                                            float* __restrict__ stat1) {
    __shared__ float xl[16 * 64];
    __shared__ float sS[128], sQ[128];
    int t = threadIdx.x, n0 = blockIdx.x * 16;
    if (t < 128) { sS[t] = 0.f; sQ[t] = 0.f; }
    for (int k = 0; k < 4; ++k) xl[t + 256 * k] = nf[(size_t)n0 * 64 + t + 256 * k];
    __syncthreads();
    int nl = t >> 4, h0 = (t & 15) * 8;
    float acc[8];
    for (int k = 0; k < 8; ++k) acc[k] = b1[h0 + k];
    for (int f = 0; f < 64; ++f) {
        float r = xl[nl * 64 + f];
        const float* wr = W1 + f * 128 + h0;
        for (int k = 0; k < 8; ++k) acc[k] = fmaf(r, wr[k], acc[k]);
    }
    for (int k = 0; k < 8; ++k) {
        float a = lrelu(acc[k]);
        act1[(size_t)(n0 + nl) * 128 + h0 + k] = a;
        atomicAdd(&sS[h0 + k], a);
        atomicAdd(&sQ[h0 + k], a * a);
    }
    __syncthreads();
    if (t < 128) atomicAdd(&stat1[t], sS[t]);
    else atomicAdd(&stat1[t], sQ[t - 128]);
}

// ---------------- node layer 2 ----------------------------------------------
__global__ __launch_bounds__(256) void k_l2(const float* __restrict__ act1,
                                            const float* __restrict__ stat1,
                                            const float* __restrict__ g1,
                                            const float* __restrict__ be1,
                                            const float* __restrict__ W2,
                                            const float* __restrict__ b2,
                                            float* __restrict__ act2,
                                            float* __restrict__ stat2) {
    __shared__ float a1n[16 * 128];
    __shared__ float sS[128], sQ[128];
    int t = threadIdx.x, n0 = blockIdx.x * 16;
    if (t < 128) { sS[t] = 0.f; sQ[t] = 0.f; }
    for (int k = 0; k < 8; ++k) {
        int e = t + 256 * k;
        int nl = e >> 7, h = e & 127;
        float m = stat1[h] * (1.f / 2048.f);
        float v = stat1[128 + h] * (1.f / 2048.f) - m * m;
        float sc = rsqrtf(v + EPSV);
        a1n[e] = (act1[(size_t)(n0 + nl) * 128 + h] - m) * sc * g1[h] + be1[h];
    }
    __syncthreads();
    int nl = t >> 4, h0 = (t & 15) * 8;
    float acc[8];
    for (int k = 0; k < 8; ++k) acc[k] = b2[h0 + k];
    for (int hi = 0; hi < 128; ++hi) {
        float r = a1n[nl * 128 + hi];
        const float* wr = W2 + hi * 128 + h0;
        for (int k = 0; k < 8; ++k) acc[k] = fmaf(r, wr[k], acc[k]);
    }
    for (int k = 0; k < 8; ++k) {
        float a = lrelu(acc[k]);
        act2[(size_t)(n0 + nl) * 128 + h0 + k] = a;
        atomicAdd(&sS[h0 + k], a);
        atomicAdd(&sQ[h0 + k], a * a);
    }
    __syncthreads();
    if (t < 128) atomicAdd(&stat2[t], sS[t]);
    else atomicAdd(&stat2[t], sQ[t - 128]);
}

// ---------------- node layer 3 + residual -> hb (bf16) -----------------------
__global__ __launch_bounds__(256) void k_l3(const float* __restrict__ act2,
                                            const float* __restrict__ stat2,
                                            const float* __restrict__ g2,
                                            const float* __restrict__ be2,
                                            const float* __restrict__ W3,
                                            const float* __restrict__ b3,
                                            const float* __restrict__ nf,
                                            short* __restrict__ hb) {
    __shared__ float a2n[16 * 128];
    int t = threadIdx.x, n0 = blockIdx.x * 16;
    for (int k = 0; k < 8; ++k) {
        int e = t + 256 * k;
        int nl = e >> 7, h = e & 127;
        float m = stat2[h] * (1.f / 2048.f);
        float v = stat2[128 + h] * (1.f / 2048.f) - m * m;
        float sc = rsqrtf(v + EPSV);
        a2n[e] = (act2[(size_t)(n0 + nl) * 128 + h] - m) * sc * g2[h] + be2[h];
    }
    __syncthreads();
    int nl = t >> 4, f0 = (t & 15) * 4;
    float acc[4] = {0.f, 0.f, 0.f, 0.f};
    for (int hi = 0; hi < 128; ++hi) {
        float r = a2n[nl * 128 + hi];
        const float* wr = W3 + hi * 64 + f0;
        for (int k = 0; k < 4; ++k) acc[k] = fmaf(r, wr[k], acc[k]);
    }
    for (int k = 0; k < 4; ++k) {
        float val = acc[k] + b3[f0 + k] + nf[(size_t)(n0 + nl) * 64 + f0 + k];
        hb[(size_t)(n0 + nl) * 64 + f0 + k] = f2bf(val);
    }
}

// ---------------- T[i] = diag(h_i) @ W5, fragment-physical -------------------
__global__ __launch_bounds__(256) void k_bi(const short* __restrict__ w5t,
                                            const short* __restrict__ hb,
                                            short* __restrict__ T) {
    int i = blockIdx.x;            // 0..2047
    int t = threadIdx.x;
    __shared__ short sHi[64];
    if (t < 8) ((short8*)sHi)[t] = ((const short8*)(hb + (size_t)i * 64))[t];
    __syncthreads();
    for (int k = 0; k < 4; ++k) {
        int c = t + 256 * k;       // chunk 0..1023
        int lane = c & 63, frag = c >> 6;
        int ks = frag & 1, quad = lane >> 4;
        int fb = ks * 32 + quad * 8;
        short8 wv = ((const short8*)w5t)[c];
        short8 hv = *(const short8*)(sHi + fb);
        short8 ov;
        for (int e = 0; e < 8; ++e) ov[e] = f2bf(bf2f(wv[e]) * bf2f(hv[e]));
        ((short8*)(T + (size_t)i * 8192))[c] = ov;
    }
}

// ---------------- BN+softmax fold -------------------------------------------
__global__ void k_mid(const float* __restrict__ SQe, const float* __restrict__ W6,
                      const float* __restrict__ b6, const float* __restrict__ g5,
                      const float* __restrict__ be5, float* __restrict__ w6d,
                      float* __restrict__ b6d) {
    __shared__ float part[128];
    int h = threadIdx.x;
    const float Ef = 2096128.f;
    float m = SQe[h] / Ef;
    float v = SQe[128 + h] / Ef - m * m;
    float s = rsqrtf(v + EPSV);
    float dW = W6[h * 2] - W6[h * 2 + 1];
    float sg = s * g5[h];
    w6d[h] = sg * dW;
    part[h] = (be5[h] - m * sg) * dW;
    __syncthreads();
    if (h == 0) {
        float acc = b6[0] - b6[1];
        for (int k = 0; k < 128; ++k) acc += part[k];
        b6d[0] = acc;
    }
}

// ---------------- diagonal zeros --------------------------------------------
__global__ __launch_bounds__(256) void k_diag(float* __restrict__ out) {
    int i = blockIdx.x * 256 + threadIdx.x;
    size_t base = ((size_t)i * NN + i) * 2;
    out[base] = 0.f;
    out[base + 1] = 0.f;
}

// ---------------- edge GEMM, barrier-free i-loop -----------------------------
// Block tile: 16 i (blockIdx.y) x 128 j (blockIdx.x). 4 waves split h (32 each).
// Per wave per i: 4 T-chunks from global (16B/lane coalesced, 1-ahead
// prefetch, NO LDS, NO barriers), 32 MFMA.
// pass1: mfma(hfr, tfr): D row=j(quad*4+r), col=h -> S/Q per h in 4 regs.
// pass2: mfma(tfr, hfr): D row=h(quad*4+r), col=j -> h-sum = in-lane fmac
//        over r,mth + 2 shfl_xor over quad.
__global__ __launch_bounds__(256) void edge_pass(
    const short* __restrict__ hb, const short* __restrict__ T,
    const float* __restrict__ b5, const float* __restrict__ w6d,
    const float* __restrict__ b6dp, float* __restrict__ SQe,
    float* __restrict__ out, int pass2)
{
    int jt = blockIdx.x, ig = blockIdx.y;
    int j0 = jt * 128, i0 = ig * 16;
    if (j0 + 127 <= i0) return;           // strictly-below-diagonal tile

    __shared__ float sDp[4][16][128];     // per-wave partial h-sums (32 KB)
    __shared__ float sP[16][128];         // probabilities (8 KB)

    int t = threadIdx.x, lane = t & 63, w = t >> 6;
    int quad = lane >> 4, col = lane & 15;

    // hb fragments: A-operand (pass1) / B-operand (pass2), same chunks
    short8 hfr[8][2];
#pragma unroll
    for (int mt = 0; mt < 8; ++mt)
#pragma unroll
        for (int ks = 0; ks < 2; ++ks)
            hfr[mt][ks] = *(const short8*)(hb + (size_t)(j0 + mt * 16 + col) * 64 + ks * 32 + quad * 8);

    const short* Tb = T + (size_t)i0 * 8192;
    int toff[2][2];
#pragma unroll
    for (int n = 0; n < 2; ++n)
#pragma unroll
        for (int ks = 0; ks < 2; ++ks)
            toff[n][ks] = ((((w * 2 + n) * 2 + ks) * 64) + lane) * 8;

    if (!pass2) {
        float b5c[2] = { b5[w * 32 + col], b5[w * 32 + 16 + col] };
        float S[2] = {0.f, 0.f}, Q[2] = {0.f, 0.f};
        bool str = (j0 <= i0 + 15);       // diagonal-straddling block

        short8 ta[2][2], tb[2][2];
#pragma unroll
        for (int n = 0; n < 2; ++n)
#pragma unroll
            for (int ks = 0; ks < 2; ++ks)
                ta[n][ks] = *(const short8*)(Tb + toff[n][ks]);

        auto body1 = [&](int i, short8 (&tc)[2][2]) {
            int igi = i0 + i;
#pragma unroll
            for (int n = 0; n < 2; ++n) {
#pragma unroll
                for (int mt = 0; mt < 8; ++mt) {
                    floatx4 c = {b5c[n], b5c[n], b5c[n], b5c[n]};
                    c = __builtin_amdgcn_mfma_f32_16x16x32_bf16(hfr[mt][0], tc[n][0], c, 0, 0, 0);
                    c = __builtin_amdgcn_mfma_f32_16x16x32_bf16(hfr[mt][1], tc[n][1], c, 0, 0, 0);
                    if (!str) {
#pragma unroll
                        for (int r = 0; r < 4; ++r) {
                            float a = lrelu(c[r]);
                            S[n] += a; Q[n] = fmaf(a, a, Q[n]);
                        }
                    } else {
#pragma unroll
                        for (int r = 0; r < 4; ++r) {
                            int j = j0 + mt * 16 + quad * 4 + r;
                            float a = (j > igi) ? lrelu(c[r]) : 0.f;
                            S[n] += a; Q[n] = fmaf(a, a, Q[n]);
                        }
                    }
                }
            }
        };

        for (int ii = 0; ii < 16; ii += 2) {
            {
                const short* Tn = Tb + (size_t)(ii + 1) * 8192;
#pragma unroll
                for (int n = 0; n < 2; ++n)
#pragma unroll
                    for (int ks = 0; ks < 2; ++ks)
                        tb[n][ks] = *(const short8*)(Tn + toff[n][ks]);
            }
            body1(ii, ta);
            if (ii + 2 < 16) {
                const short* Tn = Tb + (size_t)(ii + 2) * 8192;
#pragma unroll
                for (int n = 0; n < 2; ++n)
#pragma unroll
                    for (int ks = 0; ks < 2; ++ks)
                        ta[n][ks] = *(const short8*)(Tn + toff[n][ks]);
            }
            body1(ii + 1, tb);
        }

#pragma unroll
        for (int n = 0; n < 2; ++n) {
            float s = S[n], q = Q[n];
            s += __shfl_xor(s, 16); s += __shfl_xor(s, 32);
            q += __shfl_xor(q, 16); q += __shfl_xor(q, 32);
            if (quad == 0) {
                atomicAdd(&SQe[w * 32 + n * 16 + col], s);
                atomicAdd(&SQe[128 + w * 32 + n * 16 + col], q);
            }
        }
    } else {
        float b5q[2][4], w6q[2][4];
#pragma unroll
        for (int m = 0; m < 2; ++m)
#pragma unroll
            for (int r = 0; r < 4; ++r) {
                int h = w * 32 + m * 16 + quad * 4 + r;
                b5q[m][r] = b5[h];
                w6q[m][r] = w6d[h];
            }

        short8 ta[2][2], tb[2][2];
#pragma unroll
        for (int n = 0; n < 2; ++n)
#pragma unroll
            for (int ks = 0; ks < 2; ++ks)
                ta[n][ks] = *(const short8*)(Tb + toff[n][ks]);

        auto body2 = [&](int i, short8 (&tc)[2][2]) {
            float dp[8];
#pragma unroll
            for (int k = 0; k < 8; ++k) dp[k] = 0.f;
#pragma unroll
            for (int m = 0; m < 2; ++m) {
#pragma unroll
                for (int nj = 0; nj < 8; ++nj) {
                    floatx4 c = {b5q[m][0], b5q[m][1], b5q[m][2], b5q[m][3]};
                    c = __builtin_amdgcn_mfma_f32_16x16x32_bf16(tc[m][0], hfr[nj][0], c, 0, 0, 0);
                    c = __builtin_amdgcn_mfma_f32_16x16x32_bf16(tc[m][1], hfr[nj][1], c, 0, 0, 0);
#pragma unroll
                    for (int r = 0; r < 4; ++r) {
                        float a = lrelu(c[r]);
                        dp[nj] = fmaf(a, w6q[m][r], dp[nj]);
                    }
                }
            }
#pragma unroll
            for (int nj = 0; nj < 8; ++nj) {
                float v = dp[nj];
                v += __shfl_xor(v, 16);
                v += __shfl_xor(v, 32);
                if (quad == 0) sDp[w][i][nj * 16 + col] = v;
            }
        };

        for (int ii = 0; ii < 16; ii += 2) {
            {
                const short* Tn = Tb + (size_t)(ii + 1) * 8192;
#pragma unroll
                for (int n = 0; n < 2; ++n)
#pragma unroll
                    for (int ks = 0; ks < 2; ++ks)
                        tb[n][ks] = *(const short8*)(Tn + toff[n][ks]);
            }
            body2(ii, ta);
            if (ii + 2 < 16) {
                const short* Tn = Tb + (size_t)(ii + 2) * 8192;
#pragma unroll
                for (int n = 0; n < 2; ++n)
#pragma unroll
                    for (int ks = 0; ks < 2; ++ks)
                        ta[n][ks] = *(const short8*)(Tn + toff[n][ks]);
            }
            body2(ii + 1, tb);
        }

        __syncthreads();
        float bb = b6dp[0];
        for (int k = 0; k < 8; ++k) {
            int e = t + 256 * k;          // 0..2047
            int il = e >> 7, jl = e & 127;
            float v = bb + sDp[0][il][jl] + sDp[1][il][jl] + sDp[2][il][jl] + sDp[3][il][jl];
            sP[il][jl] = 1.f / (1.f + __expf(-v));
        }
        __syncthreads();

        int jl = t >> 1, cc = t & 1;
        for (int i = 0; i < 16; ++i) {     // direct rows: coalesced 1 KB
            int i_glob = i0 + i, j_glob = j0 + jl;
            if (j_glob > i_glob) {
                float p = sP[i][jl];
                out[((size_t)i_glob * NN + j_glob) * 2 + cc] = cc ? 1.f - p : p;
            }
        }
        for (int rep = 0; rep < 16; ++rep) {  // mirror: 128 B per j-row
            int jr = rep * 8 + (t >> 5);
            int inner = t & 31;
            int il = inner >> 1, c2 = inner & 1;
            int j_glob = j0 + jr, i_glob = i0 + il;
            if (j_glob > i_glob) {
                float p = sP[il][jr];
                out[((size_t)j_glob * NN + i_glob) * 2 + c2] = c2 ? 1.f - p : p;
            }
        }
    }
}

// ---------------------------------------------------------------------------
extern "C" void kernel_launch(void* const* d_in, const int* in_sizes, int n_in,
                              void* d_out, int out_size, void* d_ws, size_t ws_size,
                              hipStream_t stream) {
    const float* nf  = (const float*)d_in[1];   // d_in[0]=x unused (ref ignores it)
    const float* W1  = (const float*)d_in[2];
    const float* b1  = (const float*)d_in[3];
    const float* g1  = (const float*)d_in[4];
    const float* be1 = (const float*)d_in[5];
    const float* W2  = (const float*)d_in[6];
    const float* b2  = (const float*)d_in[7];
    const float* g2  = (const float*)d_in[8];
    const float* be2 = (const float*)d_in[9];
    const float* W3  = (const float*)d_in[10];
    const float* b3  = (const float*)d_in[11];
    const float* W5  = (const float*)d_in[12];
    const float* b5  = (const float*)d_in[13];
    const float* g5  = (const float*)d_in[14];
    const float* be5 = (const float*)d_in[15];
    const float* W6  = (const float*)d_in[16];
    const float* b6  = (const float*)d_in[17];
    float* out = (float*)d_out;

    float* wsf   = (float*)d_ws;
    float* stat1 = wsf;                 // 256
    float* stat2 = wsf + 256;           // 256
    float* SQe   = wsf + 512;           // 256
    float* w6d   = wsf + 768;           // 128
    float* b6dp  = wsf + 896;           // 1 (pad to 1024)
    float* act1  = wsf + 1024;          // 262144
    float* act2  = act1 + 262144;       // 262144
    short* hb    = (short*)(act2 + 262144);   // 131072 bf16
    short* w5t   = hb + 131072;               // 8192 bf16
    short* Tbuf  = w5t + 8192;                // 2048*8192 bf16 = 32 MB

    hipMemsetAsync(d_ws, 0, 1024 * sizeof(float), stream);

    k_w5t<<<32, 256, 0, stream>>>(W5, w5t);
    k_l1<<<128, 256, 0, stream>>>(nf, W1, b1, act1, stat1);
    k_l2<<<128, 256, 0, stream>>>(act1, stat1, g1, be1, W2, b2, act2, stat2);
    k_l3<<<128, 256, 0, stream>>>(act2, stat2, g2, be2, W3, b3, nf, hb);
    k_bi<<<2048, 256, 0, stream>>>(w5t, hb, Tbuf);

    dim3 grid(16, 128);
    edge_pass<<<grid, 256, 0, stream>>>(hb, Tbuf, b5, w6d, b6dp, SQe, out, 0);
    k_mid<<<1, 128, 0, stream>>>(SQe, W6, b6, g5, be5, w6d, b6dp);
    edge_pass<<<grid, 256, 0, stream>>>(hb, Tbuf, b5, w6d, b6dp, SQe, out, 1);
    k_diag<<<8, 256, 0, stream>>>(out);
}

// Round 3
// 327.108 us; speedup vs baseline: 2.6717x; 1.2728x over previous
//
#include <hip/hip_runtime.h>
#include <hip/hip_bf16.h>

// ---------------------------------------------------------------------------
// ramsey_NN: node MLP (3 layers, train-mode BN) + all-pairs edge head.
// N=2048, F=64, H=128, C=2.  E = N(N-1)/2 = 2096128.
//
// R3 vs R2 (R2 was beyond-L2-traffic bound: hbm_bytes == logical T traffic
// 139 MB @ 940 GB/s == 147 us):
//   * edge kernels: 1-D grid of EXACTLY the 1088 active tiles, swizzled so
//     all j-blocks of row ig land on XCD ig%8 (blockIdx%8 heuristic), making
//     the per-row 128 KB T slab L2-resident -> beyond-L2 T traffic ~17 MB.
//   * pass1/pass2 split into two kernels (pass1 LDS 1 KB; pass2 8 KB via
//     ds_add_f32 partial sums instead of 32 KB sDp).
//   * k_w5t fused into k_bi (W5 staged in LDS once per block).
//   * k_diag fused into pass2 (j==i writes 0).
//   * node kernels widened to 256 blocks.
// ---------------------------------------------------------------------------

typedef short short8 __attribute__((ext_vector_type(8)));   // 8 x bf16
typedef float floatx4 __attribute__((ext_vector_type(4)));  // MFMA C/D

#define NN 2048
#define EPSV 1e-5f
#define SLOPE 0.01f

__device__ __forceinline__ float bf2f(short s) {
    return __uint_as_float(((unsigned)(unsigned short)s) << 16);
}
__device__ __forceinline__ short f2bf(float f) {   // RNE
    unsigned u = __float_as_uint(f);
    unsigned r = (u + 0x7FFFu + ((u >> 16) & 1u)) >> 16;
    return (short)r;
}
__device__ __forceinline__ float lrelu(float x) { return fmaxf(x, SLOPE * x); }

// fragment-physical index (16x16x32 bf16 A/B identity layout)
__device__ __forceinline__ int physB(int h, int f) {
    return ((((h >> 4) * 2 + (f >> 5)) * 64 + ((f >> 3) & 3) * 16 + (h & 15)) * 8) + (f & 7);
}

// decode 1-D active-tile index -> (i0, j0); row ig bound to XCD ig%8.
// Row ig has 16 - ig/8 active j-tiles (jt >= ig/8). Per-XCD slots: 136.
__device__ __forceinline__ void decode_tile(int bid, int& i0, int& j0) {
    int xcd = bid & 7, s = bid >> 3;
    int m = 0, c = 0;
#pragma unroll 1
    while (s - c >= 16 - m) { c += 16 - m; ++m; }
    int ig = xcd + (m << 3);
    int jt = m + (s - c);
    i0 = ig * 16; j0 = jt * 128;
}

// ---------------- node layer 1 (256 blocks x 8 nodes) ------------------------
__global__ __launch_bounds__(256) void k_l1(const float* __restrict__ nf,
                                            const float* __restrict__ W1,
                                            const float* __restrict__ b1,
                                            float* __restrict__ act1,
                                            float* __restrict__ stat1) {
    __shared__ float xl[8 * 64];
    __shared__ float sS[128], sQ[128];
    int t = threadIdx.x, n0 = blockIdx.x * 8;
    if (t < 128) { sS[t] = 0.f; sQ[t] = 0.f; }
    xl[t] = nf[(size_t)n0 * 64 + t];
    xl[t + 256] = nf[(size_t)n0 * 64 + t + 256];
    __syncthreads();
    int nl = t >> 5, h0 = (t & 31) * 4;
    float acc[4];
    for (int k = 0; k < 4; ++k) acc[k] = b1[h0 + k];
    for (int f = 0; f < 64; ++f) {
        float r = xl[nl * 64 + f];
        const float* wr = W1 + f * 128 + h0;
        for (int k = 0; k < 4; ++k) acc[k] = fmaf(r, wr[k], acc[k]);
    }
    for (int k = 0; k < 4; ++k) {
        float a = lrelu(acc[k]);
        act1[(size_t)(n0 + nl) * 128 + h0 + k] = a;
        atomicAdd(&sS[h0 + k], a);
        atomicAdd(&sQ[h0 + k], a * a);
    }
    __syncthreads();
    if (t < 128) atomicAdd(&stat1[t], sS[t]);
    else atomicAdd(&stat1[t], sQ[t - 128]);
}

// ---------------- node layer 2 ----------------------------------------------
__global__ __launch_bounds__(256) void k_l2(const float* __restrict__ act1,
                                            const float* __restrict__ stat1,
                                            const float* __restrict__ g1,
                                            const float* __restrict__ be1,
                                            const float* __restrict__ W2,
                                            const float* __restrict__ b2,
                                            float* __restrict__ act2,
                                            float* __restrict__ stat2) {
    __shared__ float a1n[8 * 128];
    __shared__ float sS[128], sQ[128];
    int t = threadIdx.x, n0 = blockIdx.x * 8;
    if (t < 128) { sS[t] = 0.f; sQ[t] = 0.f; }
    for (int k = 0; k < 4; ++k) {
        int e = t + 256 * k;
        int nl = e >> 7, h = e & 127;
        float m = stat1[h] * (1.f / 2048.f);
        float v = stat1[128 + h] * (1.f / 2048.f) - m * m;
        float sc = rsqrtf(v + EPSV);
        a1n[e] = (act1[(size_t)(n0 + nl) * 128 + h] - m) * sc * g1[h] + be1[h];
    }
    __syncthreads();
    int nl = t >> 5, h0 = (t & 31) * 4;
    float acc[4];
    for (int k = 0; k < 4; ++k) acc[k] = b2[h0 + k];
    for (int hi = 0; hi < 128; ++hi) {
        float r = a1n[nl * 128 + hi];
        const float* wr = W2 + hi * 128 + h0;
        for (int k = 0; k < 4; ++k) acc[k] = fmaf(r, wr[k], acc[k]);
    }
    for (int k = 0; k < 4; ++k) {
        float a = lrelu(acc[k]);
        act2[(size_t)(n0 + nl) * 128 + h0 + k] = a;
        atomicAdd(&sS[h0 + k], a);
        atomicAdd(&sQ[h0 + k], a * a);
    }
    __syncthreads();
    if (t < 128) atomicAdd(&stat2[t], sS[t]);
    else atomicAdd(&stat2[t], sQ[t - 128]);
}

// ---------------- node layer 3 + residual -> hb (bf16) -----------------------
__global__ __launch_bounds__(256) void k_l3(const float* __restrict__ act2,
                                            const float* __restrict__ stat2,
                                            const float* __restrict__ g2,
                                            const float* __restrict__ be2,
                                            const float* __restrict__ W3,
                                            const float* __restrict__ b3,
                                            const float* __restrict__ nf,
                                            short* __restrict__ hb) {
    __shared__ float a2n[8 * 128];
    int t = threadIdx.x, n0 = blockIdx.x * 8;
    for (int k = 0; k < 4; ++k) {
        int e = t + 256 * k;
        int nl = e >> 7, h = e & 127;
        float m = stat2[h] * (1.f / 2048.f);
        float v = stat2[128 + h] * (1.f / 2048.f) - m * m;
        float sc = rsqrtf(v + EPSV);
        a2n[e] = (act2[(size_t)(n0 + nl) * 128 + h] - m) * sc * g2[h] + be2[h];
    }
    __syncthreads();
    int nl = t >> 5, f0 = (t & 31) * 2;
    float acc[2] = {0.f, 0.f};
    for (int hi = 0; hi < 128; ++hi) {
        float r = a2n[nl * 128 + hi];
        const float* wr = W3 + hi * 64 + f0;
        acc[0] = fmaf(r, wr[0], acc[0]);
        acc[1] = fmaf(r, wr[1], acc[1]);
    }
    float v0 = acc[0] + b3[f0] + nf[(size_t)(n0 + nl) * 64 + f0];
    float v1 = acc[1] + b3[f0 + 1] + nf[(size_t)(n0 + nl) * 64 + f0 + 1];
    unsigned p = (unsigned)(unsigned short)f2bf(v0) |
                 ((unsigned)(unsigned short)f2bf(v1) << 16);
    ((unsigned*)hb)[(size_t)(n0 + nl) * 32 + (f0 >> 1)] = p;
}

// ---------------- T[i] = diag(h_i) @ W5 (W5 cvt fused, 256 blocks x 8 i) -----
__global__ __launch_bounds__(256) void k_bi(const float* __restrict__ W5,
                                            const short* __restrict__ hb,
                                            short* __restrict__ T) {
    __shared__ short sW[8192];      // W5 bf16, fragment-physical
    __shared__ short sH[8 * 64];    // 8 node rows
    int t = threadIdx.x, i0 = blockIdx.x * 8;
    for (int k = 0; k < 32; ++k) {
        int idx = t + 256 * k;              // f*128+h
        int h = idx & 127, f = idx >> 7;
        sW[physB(h, f)] = f2bf(W5[idx]);
    }
    ((int*)sH)[t] = ((const int*)(hb + (size_t)i0 * 64))[t];   // 1 KB
    __syncthreads();
    for (int i = 0; i < 8; ++i) {
        for (int k = 0; k < 4; ++k) {
            int c = t + 256 * k;            // chunk 0..1023
            int lane = c & 63, frag = c >> 6;
            int ks = frag & 1, quad = lane >> 4;
            int fb = ks * 32 + quad * 8;
            short8 wv = ((const short8*)sW)[c];
            short8 hv = *(const short8*)(sH + i * 64 + fb);
            short8 ov;
            for (int e = 0; e < 8; ++e) ov[e] = f2bf(bf2f(wv[e]) * bf2f(hv[e]));
            ((short8*)(T + (size_t)(i0 + i) * 8192))[c] = ov;
        }
    }
}

// ---------------- BN+softmax fold -------------------------------------------
__global__ void k_mid(const float* __restrict__ SQe, const float* __restrict__ W6,
                      const float* __restrict__ b6, const float* __restrict__ g5,
                      const float* __restrict__ be5, float* __restrict__ w6d,
                      float* __restrict__ b6d) {
    __shared__ float part[128];
    int h = threadIdx.x;
    const float Ef = 2096128.f;
    float m = SQe[h] / Ef;
    float v = SQe[128 + h] / Ef - m * m;
    float s = rsqrtf(v + EPSV);
    float dW = W6[h * 2] - W6[h * 2 + 1];
    float sg = s * g5[h];
    w6d[h] = sg * dW;
    part[h] = (be5[h] - m * sg) * dW;
    __syncthreads();
    if (h == 0) {
        float acc = b6[0] - b6[1];
        for (int k = 0; k < 128; ++k) acc += part[k];
        b6d[0] = acc;
    }
}

// ---------------- edge pass 1: BN stats over upper triangle ------------------
__global__ __launch_bounds__(256) void edge_p1(
    const short* __restrict__ hb, const short* __restrict__ T,
    const float* __restrict__ b5, float* __restrict__ SQe)
{
    int i0, j0;
    decode_tile(blockIdx.x, i0, j0);
    __shared__ float sS[128], sQ[128];

    int t = threadIdx.x, lane = t & 63, w = t >> 6;
    int quad = lane >> 4, col = lane & 15;
    if (t < 128) { sS[t] = 0.f; sQ[t] = 0.f; }
    __syncthreads();

    short8 hfr[8][2];
#pragma unroll
    for (int mt = 0; mt < 8; ++mt)
#pragma unroll
        for (int ks = 0; ks < 2; ++ks)
            hfr[mt][ks] = *(const short8*)(hb + (size_t)(j0 + mt * 16 + col) * 64 + ks * 32 + quad * 8);

    const short* Tb = T + (size_t)i0 * 8192;
    int toff[2][2];
#pragma unroll
    for (int n = 0; n < 2; ++n)
#pragma unroll
        for (int ks = 0; ks < 2; ++ks)
            toff[n][ks] = ((((w * 2 + n) * 2 + ks) * 64) + lane) * 8;

    float b5c[2] = { b5[w * 32 + col], b5[w * 32 + 16 + col] };
    float S[2] = {0.f, 0.f}, Q[2] = {0.f, 0.f};
    bool str = (j0 <= i0 + 15);

    short8 ta[2][2], tb[2][2];
#pragma unroll
    for (int n = 0; n < 2; ++n)
#pragma unroll
        for (int ks = 0; ks < 2; ++ks)
            ta[n][ks] = *(const short8*)(Tb + toff[n][ks]);

    auto body1 = [&](int i, short8 (&tc)[2][2]) {
        int igi = i0 + i;
#pragma unroll
        for (int n = 0; n < 2; ++n) {
#pragma unroll
            for (int mt = 0; mt < 8; ++mt) {
                floatx4 c = {b5c[n], b5c[n], b5c[n], b5c[n]};
                c = __builtin_amdgcn_mfma_f32_16x16x32_bf16(hfr[mt][0], tc[n][0], c, 0, 0, 0);
                c = __builtin_amdgcn_mfma_f32_16x16x32_bf16(hfr[mt][1], tc[n][1], c, 0, 0, 0);
                if (!str) {
#pragma unroll
                    for (int r = 0; r < 4; ++r) {
                        float a = lrelu(c[r]);
                        S[n] += a; Q[n] = fmaf(a, a, Q[n]);
                    }
                } else {
#pragma unroll
                    for (int r = 0; r < 4; ++r) {
                        int j = j0 + mt * 16 + quad * 4 + r;
                        float a = (j > igi) ? lrelu(c[r]) : 0.f;
                        S[n] += a; Q[n] = fmaf(a, a, Q[n]);
                    }
                }
            }
        }
    };

    for (int ii = 0; ii < 16; ii += 2) {
        {
            const short* Tn = Tb + (size_t)(ii + 1) * 8192;
#pragma unroll
            for (int n = 0; n < 2; ++n)
#pragma unroll
                for (int ks = 0; ks < 2; ++ks)
                    tb[n][ks] = *(const short8*)(Tn + toff[n][ks]);
        }
        body1(ii, ta);
        if (ii + 2 < 16) {
            const short* Tn = Tb + (size_t)(ii + 2) * 8192;
#pragma unroll
            for (int n = 0; n < 2; ++n)
#pragma unroll
                for (int ks = 0; ks < 2; ++ks)
                    ta[n][ks] = *(const short8*)(Tn + toff[n][ks]);
        }
        body1(ii + 1, tb);
    }

#pragma unroll
    for (int n = 0; n < 2; ++n) {
        float s = S[n], q = Q[n];
        s += __shfl_xor(s, 16); s += __shfl_xor(s, 32);
        q += __shfl_xor(q, 16); q += __shfl_xor(q, 32);
        if (quad == 0) {
            atomicAdd(&sS[w * 32 + n * 16 + col], s);
            atomicAdd(&sQ[w * 32 + n * 16 + col], q);
        }
    }
    __syncthreads();
    if (t < 128) atomicAdd(&SQe[t], sS[t]);
    else atomicAdd(&SQe[t], sQ[t - 128]);
}

// ---------------- edge pass 2: probabilities + symmetric write ---------------
__global__ __launch_bounds__(256) void edge_p2(
    const short* __restrict__ hb, const short* __restrict__ T,
    const float* __restrict__ b5, const float* __restrict__ w6d,
    const float* __restrict__ b6dp, float* __restrict__ out)
{
    int i0, j0;
    decode_tile(blockIdx.x, i0, j0);
    __shared__ float sV[16][128];     // partial h-sums (8 KB)

    int t = threadIdx.x, lane = t & 63, w = t >> 6;
    int quad = lane >> 4, col = lane & 15;
    for (int k = 0; k < 8; ++k) ((float*)sV)[t + 256 * k] = 0.f;
    __syncthreads();

    short8 hfr[8][2];
#pragma unroll
    for (int mt = 0; mt < 8; ++mt)
#pragma unroll
        for (int ks = 0; ks < 2; ++ks)
            hfr[mt][ks] = *(const short8*)(hb + (size_t)(j0 + mt * 16 + col) * 64 + ks * 32 + quad * 8);

    const short* Tb = T + (size_t)i0 * 8192;
    int toff[2][2];
#pragma unroll
    for (int m = 0; m < 2; ++m)
#pragma unroll
        for (int ks = 0; ks < 2; ++ks)
            toff[m][ks] = ((((w * 2 + m) * 2 + ks) * 64) + lane) * 8;

    float b5q[2][4], w6q[2][4];
#pragma unroll
    for (int m = 0; m < 2; ++m)
#pragma unroll
        for (int r = 0; r < 4; ++r) {
            int h = w * 32 + m * 16 + quad * 4 + r;
            b5q[m][r] = b5[h];
            w6q[m][r] = w6d[h];
        }

    short8 ta[2][2], tb[2][2];
#pragma unroll
    for (int m = 0; m < 2; ++m)
#pragma unroll
        for (int ks = 0; ks < 2; ++ks)
            ta[m][ks] = *(const short8*)(Tb + toff[m][ks]);

    auto body2 = [&](int i, short8 (&tc)[2][2]) {
        float dp[8];
#pragma unroll
        for (int k = 0; k < 8; ++k) dp[k] = 0.f;
#pragma unroll
        for (int m = 0; m < 2; ++m) {
#pragma unroll
            for (int nj = 0; nj < 8; ++nj) {
                floatx4 c = {b5q[m][0], b5q[m][1], b5q[m][2], b5q[m][3]};
                c = __builtin_amdgcn_mfma_f32_16x16x32_bf16(tc[m][0], hfr[nj][0], c, 0, 0, 0);
                c = __builtin_amdgcn_mfma_f32_16x16x32_bf16(tc[m][1], hfr[nj][1], c, 0, 0, 0);
#pragma unroll
                for (int r = 0; r < 4; ++r) {
                    float a = lrelu(c[r]);
                    dp[nj] = fmaf(a, w6q[m][r], dp[nj]);
                }
            }
        }
#pragma unroll
        for (int nj = 0; nj < 8; ++nj) {
            float v = dp[nj];
            v += __shfl_xor(v, 16);
            v += __shfl_xor(v, 32);
            if (quad == 0) atomicAdd(&sV[i][nj * 16 + col], v);
        }
    };

    for (int ii = 0; ii < 16; ii += 2) {
        {
            const short* Tn = Tb + (size_t)(ii + 1) * 8192;
#pragma unroll
            for (int m = 0; m < 2; ++m)
#pragma unroll
                for (int ks = 0; ks < 2; ++ks)
                    tb[m][ks] = *(const short8*)(Tn + toff[m][ks]);
        }
        body2(ii, ta);
        if (ii + 2 < 16) {
            const short* Tn = Tb + (size_t)(ii + 2) * 8192;
#pragma unroll
            for (int m = 0; m < 2; ++m)
#pragma unroll
                for (int ks = 0; ks < 2; ++ks)
                    ta[m][ks] = *(const short8*)(Tn + toff[m][ks]);
        }
        body2(ii + 1, tb);
    }

    __syncthreads();
    float bb = b6dp[0];
    int jl = t >> 1, cc = t & 1;
    for (int i = 0; i < 16; ++i) {        // direct rows (incl. diagonal zeros)
        int i_glob = i0 + i, j_glob = j0 + jl;
        if (j_glob >= i_glob) {
            float p = 1.f / (1.f + __expf(-(bb + sV[i][jl])));
            float val = (j_glob == i_glob) ? 0.f : (cc ? 1.f - p : p);
            out[((size_t)i_glob * NN + j_glob) * 2 + cc] = val;
        }
    }
    for (int rep = 0; rep < 16; ++rep) {  // mirror
        int jr = rep * 8 + (t >> 5);
        int inner = t & 31;
        int il = inner >> 1, c2 = inner & 1;
        int j_glob = j0 + jr, i_glob = i0 + il;
        if (j_glob > i_glob) {
            float p = 1.f / (1.f + __expf(-(bb + sV[il][jr])));
            out[((size_t)j_glob * NN + i_glob) * 2 + c2] = c2 ? 1.f - p : p;
        }
    }
}

// ---------------------------------------------------------------------------
extern "C" void kernel_launch(void* const* d_in, const int* in_sizes, int n_in,
                              void* d_out, int out_size, void* d_ws, size_t ws_size,
                              hipStream_t stream) {
    const float* nf  = (const float*)d_in[1];   // d_in[0]=x unused (ref ignores it)
    const float* W1  = (const float*)d_in[2];
    const float* b1  = (const float*)d_in[3];
    const float* g1  = (const float*)d_in[4];
    const float* be1 = (const float*)d_in[5];
    const float* W2  = (const float*)d_in[6];
    const float* b2  = (const float*)d_in[7];
    const float* g2  = (const float*)d_in[8];
    const float* be2 = (const float*)d_in[9];
    const float* W3  = (const float*)d_in[10];
    const float* b3  = (const float*)d_in[11];
    const float* W5  = (const float*)d_in[12];
    const float* b5  = (const float*)d_in[13];
    const float* g5  = (const float*)d_in[14];
    const float* be5 = (const float*)d_in[15];
    const float* W6  = (const float*)d_in[16];
    const float* b6  = (const float*)d_in[17];
    float* out = (float*)d_out;

    float* wsf   = (float*)d_ws;
    float* stat1 = wsf;                 // 256
    float* stat2 = wsf + 256;           // 256
    float* SQe   = wsf + 512;           // 256
    float* w6d   = wsf + 768;           // 128
    float* b6dp  = wsf + 896;           // 1 (pad to 1024)
    float* act1  = wsf + 1024;          // 262144
    float* act2  = act1 + 262144;       // 262144
    short* hb    = (short*)(act2 + 262144);   // 131072 bf16
    short* Tbuf  = hb + 131072;               // 2048*8192 bf16 = 32 MB

    hipMemsetAsync(d_ws, 0, 1024 * sizeof(float), stream);

    k_l1<<<256, 256, 0, stream>>>(nf, W1, b1, act1, stat1);
    k_l2<<<256, 256, 0, stream>>>(act1, stat1, g1, be1, W2, b2, act2, stat2);
    k_l3<<<256, 256, 0, stream>>>(act2, stat2, g2, be2, W3, b3, nf, hb);
    k_bi<<<256, 256, 0, stream>>>(W5, hb, Tbuf);

    edge_p1<<<1088, 256, 0, stream>>>(hb, Tbuf, b5, SQe);
    k_mid<<<1, 128, 0, stream>>>(SQe, W6, b6, g5, be5, w6d, b6dp);
    edge_p2<<<1088, 256, 0, stream>>>(hb, Tbuf, b5, w6d, b6dp, out);
}

// Round 4
// 267.440 us; speedup vs baseline: 3.2678x; 1.2231x over previous
//
#include <hip/hip_runtime.h>
#include <hip/hip_bf16.h>

// ---------------------------------------------------------------------------
// ramsey_NN: node MLP (3 layers, train-mode BN) + all-pairs edge head.
// N=2048, F=64, H=128, C=2.  E = N(N-1)/2 = 2096128.
//
// R4 vs R3 (R3 was occupancy/latency-bound: Occ 16.8%, real regs ~150):
//   * edge tiles 8i x 64j -> 4224 blocks (3x wave supply), hfr regs halved.
//   * p2 epilogue: lrelu(z)*w = z*(.505w) + |z|*(.495w)  (2 fma, abs free).
//   * k_mid fused into p2 prologue; k_bi fused into k_l3 (same partition).
//   * p1 stats -> per-XCD copies SQe8[8][256] (atomic contention /8).
//   * padded sP[8][65]; float4 output stores on non-straddle tiles.
// ---------------------------------------------------------------------------

typedef short short8 __attribute__((ext_vector_type(8)));   // 8 x bf16
typedef float floatx4 __attribute__((ext_vector_type(4)));  // MFMA C/D

#define NN 2048
#define EPSV 1e-5f
#define EDGEF 2096128.f

__device__ __forceinline__ float bf2f(short s) {
    return __uint_as_float(((unsigned)(unsigned short)s) << 16);
}
__device__ __forceinline__ short f2bf(float f) {   // RNE
    unsigned u = __float_as_uint(f);
    unsigned r = (u + 0x7FFFu + ((u >> 16) & 1u)) >> 16;
    return (short)r;
}
__device__ __forceinline__ float lrelu(float x) { return fmaxf(x, 0.01f * x); }

// fragment-physical chunk index (16x16x32 bf16, A/B identity layout)
__device__ __forceinline__ int physB(int h, int f) {
    return ((((h >> 4) * 2 + (f >> 5)) * 64 + ((f >> 3) & 3) * 16 + (h & 15)) * 8) + (f & 7);
}

// 1-D active-tile decode: rows-of-8 nodes (ig8 in [0,256)), j-tiles of 64.
// Row ig8 pinned to XCD ig8%8 (blockIdx%8 round-robin heuristic).
// Per-XCD slots: sum_{m=0}^{31} (32-m) = 528; grid = 8*528 = 4224.
__device__ __forceinline__ void decode_tile(int bid, int& i0, int& j0, bool& str) {
    int s = bid >> 3, m = 0;
#pragma unroll 1
    while (s >= 32 - m) { s -= 32 - m; ++m; }
    i0 = ((bid & 7) + (m << 3)) * 8;
    j0 = (m + s) * 64;
    str = (s == 0);          // diagonal-straddling tile (jt == m)
}

// ---------------- node layer 1 (256 blocks x 8 nodes) ------------------------
__global__ __launch_bounds__(256) void k_l1(const float* __restrict__ nf,
                                            const float* __restrict__ W1,
                                            const float* __restrict__ b1,
                                            float* __restrict__ act1,
                                            float* __restrict__ stat1) {
    __shared__ float xl[8 * 64];
    __shared__ float sS[128], sQ[128];
    int t = threadIdx.x, n0 = blockIdx.x * 8;
    if (t < 128) { sS[t] = 0.f; sQ[t] = 0.f; }
    xl[t] = nf[(size_t)n0 * 64 + t];
    xl[t + 256] = nf[(size_t)n0 * 64 + t + 256];
    __syncthreads();
    int nl = t >> 5, h0 = (t & 31) * 4;
    float acc[4];
    for (int k = 0; k < 4; ++k) acc[k] = b1[h0 + k];
    for (int f = 0; f < 64; ++f) {
        float r = xl[nl * 64 + f];
        const float* wr = W1 + f * 128 + h0;
        for (int k = 0; k < 4; ++k) acc[k] = fmaf(r, wr[k], acc[k]);
    }
    for (int k = 0; k < 4; ++k) {
        float a = lrelu(acc[k]);
        act1[(size_t)(n0 + nl) * 128 + h0 + k] = a;
        atomicAdd(&sS[h0 + k], a);
        atomicAdd(&sQ[h0 + k], a * a);
    }
    __syncthreads();
    if (t < 128) atomicAdd(&stat1[t], sS[t]);
    else atomicAdd(&stat1[t], sQ[t - 128]);
}

// ---------------- node layer 2 ----------------------------------------------
__global__ __launch_bounds__(256) void k_l2(const float* __restrict__ act1,
                                            const float* __restrict__ stat1,
                                            const float* __restrict__ g1,
                                            const float* __restrict__ be1,
                                            const float* __restrict__ W2,
                                            const float* __restrict__ b2,
                                            float* __restrict__ act2,
                                            float* __restrict__ stat2) {
    __shared__ float a1n[8 * 128];
    __shared__ float sS[128], sQ[128];
    int t = threadIdx.x, n0 = blockIdx.x * 8;
    if (t < 128) { sS[t] = 0.f; sQ[t] = 0.f; }
    for (int k = 0; k < 4; ++k) {
        int e = t + 256 * k;
        int nl = e >> 7, h = e & 127;
        float m = stat1[h] * (1.f / 2048.f);
        float v = stat1[128 + h] * (1.f / 2048.f) - m * m;
        float sc = rsqrtf(v + EPSV);
        a1n[e] = (act1[(size_t)(n0 + nl) * 128 + h] - m) * sc * g1[h] + be1[h];
    }
    __syncthreads();
    int nl = t >> 5, h0 = (t & 31) * 4;
    float acc[4];
    for (int k = 0; k < 4; ++k) acc[k] = b2[h0 + k];
    for (int hi = 0; hi < 128; ++hi) {
        float r = a1n[nl * 128 + hi];
        const float* wr = W2 + hi * 128 + h0;
        for (int k = 0; k < 4; ++k) acc[k] = fmaf(r, wr[k], acc[k]);
    }
    for (int k = 0; k < 4; ++k) {
        float a = lrelu(acc[k]);
        act2[(size_t)(n0 + nl) * 128 + h0 + k] = a;
        atomicAdd(&sS[h0 + k], a);
        atomicAdd(&sQ[h0 + k], a * a);
    }
    __syncthreads();
    if (t < 128) atomicAdd(&stat2[t], sS[t]);
    else atomicAdd(&stat2[t], sQ[t - 128]);
}

// ---------------- layer 3 + residual + T-build (fused, 256 blocks x 8) -------
__global__ __launch_bounds__(256) void k_l3b(const float* __restrict__ act2,
                                             const float* __restrict__ stat2,
                                             const float* __restrict__ g2,
                                             const float* __restrict__ be2,
                                             const float* __restrict__ W3,
                                             const float* __restrict__ b3,
                                             const float* __restrict__ nf,
                                             const float* __restrict__ W5,
                                             short* __restrict__ hb,
                                             short* __restrict__ T) {
    __shared__ float a2n[8 * 128];
    __shared__ short sW[8192];      // W5 bf16, fragment-physical
    __shared__ short sH[8 * 64];    // this block's hb rows
    int t = threadIdx.x, n0 = blockIdx.x * 8;
    for (int k = 0; k < 32; ++k) {            // W5 -> bf16 frag-physical
        int idx = t + 256 * k;                // f*128+h
        sW[physB(idx & 127, idx >> 7)] = f2bf(W5[idx]);
    }
    for (int k = 0; k < 4; ++k) {
        int e = t + 256 * k;
        int nl = e >> 7, h = e & 127;
        float m = stat2[h] * (1.f / 2048.f);
        float v = stat2[128 + h] * (1.f / 2048.f) - m * m;
        float sc = rsqrtf(v + EPSV);
        a2n[e] = (act2[(size_t)(n0 + nl) * 128 + h] - m) * sc * g2[h] + be2[h];
    }
    __syncthreads();
    int nl = t >> 5, f0 = (t & 31) * 2;
    float acc[2] = {0.f, 0.f};
    for (int hi = 0; hi < 128; ++hi) {
        float r = a2n[nl * 128 + hi];
        const float* wr = W3 + hi * 64 + f0;
        acc[0] = fmaf(r, wr[0], acc[0]);
        acc[1] = fmaf(r, wr[1], acc[1]);
    }
    float v0 = acc[0] + b3[f0] + nf[(size_t)(n0 + nl) * 64 + f0];
    float v1 = acc[1] + b3[f0 + 1] + nf[(size_t)(n0 + nl) * 64 + f0 + 1];
    short s0 = f2bf(v0), s1 = f2bf(v1);
    sH[nl * 64 + f0] = s0;
    sH[nl * 64 + f0 + 1] = s1;
    unsigned p = (unsigned)(unsigned short)s0 | ((unsigned)(unsigned short)s1 << 16);
    ((unsigned*)hb)[(size_t)(n0 + nl) * 32 + (f0 >> 1)] = p;
    __syncthreads();
    for (int i = 0; i < 8; ++i) {             // T[i] = diag(h_i) @ W5
        for (int k = 0; k < 4; ++k) {
            int c = t + 256 * k;              // chunk 0..1023
            int lane = c & 63, frag = c >> 6;
            int ks = frag & 1, quad = lane >> 4;
            int fb = ks * 32 + quad * 8;
            short8 wv = ((const short8*)sW)[c];
            short8 hv = *(const short8*)(sH + i * 64 + fb);
            short8 ov;
            for (int e = 0; e < 8; ++e) ov[e] = f2bf(bf2f(wv[e]) * bf2f(hv[e]));
            ((short8*)(T + (size_t)(n0 + i) * 8192))[c] = ov;
        }
    }
}

// ---------------- edge pass 1: BN stats over upper triangle ------------------
__global__ __launch_bounds__(256) void edge_p1(
    const short* __restrict__ hb, const short* __restrict__ T,
    const float* __restrict__ b5, float* __restrict__ SQe8)
{
    int i0, j0; bool str;
    decode_tile(blockIdx.x, i0, j0, str);
    __shared__ float sS[128], sQ[128];

    int t = threadIdx.x, lane = t & 63, w = t >> 6;
    int quad = lane >> 4, col = lane & 15;
    if (t < 128) { sS[t] = 0.f; sQ[t] = 0.f; }
    __syncthreads();

    short8 hfr[4][2];
#pragma unroll
    for (int mt = 0; mt < 4; ++mt)
#pragma unroll
        for (int ks = 0; ks < 2; ++ks)
            hfr[mt][ks] = *(const short8*)(hb + (size_t)(j0 + mt * 16 + col) * 64 + ks * 32 + quad * 8);

    const short* Tb = T + (size_t)i0 * 8192;
    int toff[2][2];
#pragma unroll
    for (int n = 0; n < 2; ++n)
#pragma unroll
        for (int ks = 0; ks < 2; ++ks)
            toff[n][ks] = ((((w * 2 + n) * 2 + ks) * 64) + lane) * 8;

    float b5c[2] = { b5[w * 32 + col], b5[w * 32 + 16 + col] };
    float S[2] = {0.f, 0.f}, Q[2] = {0.f, 0.f};

    short8 ta[2][2], tb[2][2];
#pragma unroll
    for (int n = 0; n < 2; ++n)
#pragma unroll
        for (int ks = 0; ks < 2; ++ks)
            ta[n][ks] = *(const short8*)(Tb + toff[n][ks]);

    auto body1 = [&](int i, short8 (&tc)[2][2]) {
        int igi = i0 + i;
#pragma unroll
        for (int n = 0; n < 2; ++n) {
#pragma unroll
            for (int mt = 0; mt < 4; ++mt) {
                floatx4 c = {b5c[n], b5c[n], b5c[n], b5c[n]};
                c = __builtin_amdgcn_mfma_f32_16x16x32_bf16(hfr[mt][0], tc[n][0], c, 0, 0, 0);
                c = __builtin_amdgcn_mfma_f32_16x16x32_bf16(hfr[mt][1], tc[n][1], c, 0, 0, 0);
                if (!str) {
#pragma unroll
                    for (int r = 0; r < 4; ++r) {
                        float a = lrelu(c[r]);
                        S[n] += a; Q[n] = fmaf(a, a, Q[n]);
                    }
                } else {
#pragma unroll
                    for (int r = 0; r < 4; ++r) {
                        int j = j0 + mt * 16 + quad * 4 + r;
                        float a = (j > igi) ? lrelu(c[r]) : 0.f;
                        S[n] += a; Q[n] = fmaf(a, a, Q[n]);
                    }
                }
            }
        }
    };

    for (int ii = 0; ii < 8; ii += 2) {
        {
            const short* Tn = Tb + (size_t)(ii + 1) * 8192;
#pragma unroll
            for (int n = 0; n < 2; ++n)
#pragma unroll
                for (int ks = 0; ks < 2; ++ks)
                    tb[n][ks] = *(const short8*)(Tn + toff[n][ks]);
        }
        body1(ii, ta);
        if (ii + 2 < 8) {
            const short* Tn = Tb + (size_t)(ii + 2) * 8192;
#pragma unroll
            for (int n = 0; n < 2; ++n)
#pragma unroll
                for (int ks = 0; ks < 2; ++ks)
                    ta[n][ks] = *(const short8*)(Tn + toff[n][ks]);
        }
        body1(ii + 1, tb);
    }

#pragma unroll
    for (int n = 0; n < 2; ++n) {
        float s = S[n], q = Q[n];
        s += __shfl_xor(s, 16); s += __shfl_xor(s, 32);
        q += __shfl_xor(q, 16); q += __shfl_xor(q, 32);
        if (quad == 0) {
            atomicAdd(&sS[w * 32 + n * 16 + col], s);
            atomicAdd(&sQ[w * 32 + n * 16 + col], q);
        }
    }
    __syncthreads();
    float* dst = SQe8 + (blockIdx.x & 7) * 256;
    if (t < 128) atomicAdd(&dst[t], sS[t]);
    else atomicAdd(&dst[t], sQ[t - 128]);
}

// ---------------- edge pass 2: probabilities + symmetric write ---------------
__global__ __launch_bounds__(256) void edge_p2(
    const short* __restrict__ hb, const short* __restrict__ T,
    const float* __restrict__ b5, const float* __restrict__ SQe8,
    const float* __restrict__ W6, const float* __restrict__ b6,
    const float* __restrict__ g5, const float* __restrict__ be5,
    float* __restrict__ out)
{
    int i0, j0; bool str;
    decode_tile(blockIdx.x, i0, j0, str);
    __shared__ float sV[8][64];       // partial h-sums (2 KB)
    __shared__ float sP[8][65];       // probs, padded (conflict-free mirror)
    __shared__ float sW6[128];
    __shared__ float sBB;

    int t = threadIdx.x, lane = t & 63, w = t >> 6;
    int quad = lane >> 4, col = lane & 15;

    ((float*)sV)[t] = 0.f;
    ((float*)sV)[t + 256] = 0.f;
    if (t < 128) {                    // fused k_mid: fold BN+softmax
        float s = 0.f, q = 0.f;
        for (int x = 0; x < 8; ++x) {
            s += SQe8[x * 256 + t];
            q += SQe8[x * 256 + 128 + t];
        }
        float m = s / EDGEF;
        float v = q / EDGEF - m * m;
        float sc = rsqrtf(v + EPSV);
        float dW = W6[2 * t] - W6[2 * t + 1];
        float sg = sc * g5[t];
        sW6[t] = sg * dW;
        ((float*)sP)[t] = (be5[t] - m * sg) * dW;   // scratch for b6d parts
    }
    __syncthreads();
    if (w == 0) {
        float v = ((float*)sP)[lane] + ((float*)sP)[lane + 64];
        v += __shfl_xor(v, 1); v += __shfl_xor(v, 2); v += __shfl_xor(v, 4);
        v += __shfl_xor(v, 8); v += __shfl_xor(v, 16); v += __shfl_xor(v, 32);
        if (lane == 0) sBB = v + b6[0] - b6[1];
    }
    __syncthreads();
    float bb = sBB;

    float b5q[2][4], w6a[2][4], w6b[2][4];
#pragma unroll
    for (int m = 0; m < 2; ++m)
#pragma unroll
        for (int r = 0; r < 4; ++r) {
            int h = w * 32 + m * 16 + quad * 4 + r;
            b5q[m][r] = b5[h];
            float wd = sW6[h];
            w6a[m][r] = 0.505f * wd;
            w6b[m][r] = 0.495f * wd;
        }

    short8 hfr[4][2];
#pragma unroll
    for (int mt = 0; mt < 4; ++mt)
#pragma unroll
        for (int ks = 0; ks < 2; ++ks)
            hfr[mt][ks] = *(const short8*)(hb + (size_t)(j0 + mt * 16 + col) * 64 + ks * 32 + quad * 8);

    const short* Tb = T + (size_t)i0 * 8192;
    int toff[2][2];
#pragma unroll
    for (int m = 0; m < 2; ++m)
#pragma unroll
        for (int ks = 0; ks < 2; ++ks)
            toff[m][ks] = ((((w * 2 + m) * 2 + ks) * 64) + lane) * 8;

    short8 ta[2][2], tb[2][2];
#pragma unroll
    for (int m = 0; m < 2; ++m)
#pragma unroll
        for (int ks = 0; ks < 2; ++ks)
            ta[m][ks] = *(const short8*)(Tb + toff[m][ks]);

    auto body2 = [&](int i, short8 (&tc)[2][2]) {
        float dp[4] = {0.f, 0.f, 0.f, 0.f};
#pragma unroll
        for (int m = 0; m < 2; ++m) {
#pragma unroll
            for (int nj = 0; nj < 4; ++nj) {
                floatx4 c = {b5q[m][0], b5q[m][1], b5q[m][2], b5q[m][3]};
                c = __builtin_amdgcn_mfma_f32_16x16x32_bf16(tc[m][0], hfr[nj][0], c, 0, 0, 0);
                c = __builtin_amdgcn_mfma_f32_16x16x32_bf16(tc[m][1], hfr[nj][1], c, 0, 0, 0);
#pragma unroll
                for (int r = 0; r < 4; ++r) {
                    float z = c[r];
                    dp[nj] = fmaf(z, w6a[m][r], dp[nj]);
                    dp[nj] = fmaf(__builtin_fabsf(z), w6b[m][r], dp[nj]);
                }
            }
        }
#pragma unroll
        for (int nj = 0; nj < 4; ++nj) {
            float v = dp[nj];
            v += __shfl_xor(v, 16);
            v += __shfl_xor(v, 32);
            if (quad == 0) atomicAdd(&sV[i][nj * 16 + col], v);
        }
    };

    for (int ii = 0; ii < 8; ii += 2) {
        {
            const short* Tn = Tb + (size_t)(ii + 1) * 8192;
#pragma unroll
            for (int m = 0; m < 2; ++m)
#pragma unroll
                for (int ks = 0; ks < 2; ++ks)
                    tb[m][ks] = *(const short8*)(Tn + toff[m][ks]);
        }
        body2(ii, ta);
        if (ii + 2 < 8) {
            const short* Tn = Tb + (size_t)(ii + 2) * 8192;
#pragma unroll
            for (int m = 0; m < 2; ++m)
#pragma unroll
                for (int ks = 0; ks < 2; ++ks)
                    ta[m][ks] = *(const short8*)(Tn + toff[m][ks]);
        }
        body2(ii + 1, tb);
    }

    __syncthreads();
    for (int k = 0; k < 2; ++k) {     // probabilities
        int e = t + 256 * k;          // 0..511
        int il = e >> 6, jl = e & 63;
        sP[il][jl] = 1.f / (1.f + __expf(-(bb + sV[il][jl])));
    }
    __syncthreads();

    if (!str) {
        // direct rows: 8 x 128 floats, float4 per thread
        {
            int i = t >> 5, f0 = (t & 31) * 4, jl = f0 >> 1;
            float p0 = sP[i][jl], p1 = sP[i][jl + 1];
            float4 v = {p0, 1.f - p0, p1, 1.f - p1};
            *(float4*)(out + ((size_t)(i0 + i) * NN + j0) * 2 + f0) = v;
        }
        // mirror: 64 rows x 16 floats, float4 per thread
        {
            int jr = t >> 2, f1 = (t & 3) * 4;
            float4 u;
#pragma unroll
            for (int e = 0; e < 4; ++e) {
                int ff = f1 + e;
                float p = sP[ff >> 1][jr];
                u[e] = (ff & 1) ? 1.f - p : p;
            }
            *(float4*)(out + ((size_t)(j0 + jr) * NN + i0) * 2 + f1) = u;
        }
    } else {
        // straddle tile: scalar guarded writes
#pragma unroll
        for (int e = 0; e < 4; ++e) {     // direct 8x64x2 = 1024 floats
            int f = t * 4 + e;
            int i = f >> 7, jl = (f & 127) >> 1, c = f & 1;
            int ig = i0 + i, jg = j0 + jl;
            if (jg > ig) {
                float p = sP[i][jl];
                out[((size_t)ig * NN + jg) * 2 + c] = c ? 1.f - p : p;
            } else if (jg == ig) {
                out[((size_t)ig * NN + jg) * 2 + c] = 0.f;
            }
        }
#pragma unroll
        for (int e = 0; e < 4; ++e) {     // mirror 64x8x2 = 1024 floats
            int f = t * 4 + e;
            int jr = f >> 4, ff = f & 15;
            int il = ff >> 1, c = ff & 1;
            int jg = j0 + jr, ig = i0 + il;
            if (jg > ig) {
                float p = sP[il][jr];
                out[((size_t)jg * NN + ig) * 2 + c] = c ? 1.f - p : p;
            }
        }
    }
}

// ---------------------------------------------------------------------------
extern "C" void kernel_launch(void* const* d_in, const int* in_sizes, int n_in,
                              void* d_out, int out_size, void* d_ws, size_t ws_size,
                              hipStream_t stream) {
    const float* nf  = (const float*)d_in[1];   // d_in[0]=x unused (ref ignores it)
    const float* W1  = (const float*)d_in[2];
    const float* b1  = (const float*)d_in[3];
    const float* g1  = (const float*)d_in[4];
    const float* be1 = (const float*)d_in[5];
    const float* W2  = (const float*)d_in[6];
    const float* b2  = (const float*)d_in[7];
    const float* g2  = (const float*)d_in[8];
    const float* be2 = (const float*)d_in[9];
    const float* W3  = (const float*)d_in[10];
    const float* b3  = (const float*)d_in[11];
    const float* W5  = (const float*)d_in[12];
    const float* b5  = (const float*)d_in[13];
    const float* g5  = (const float*)d_in[14];
    const float* be5 = (const float*)d_in[15];
    const float* W6  = (const float*)d_in[16];
    const float* b6  = (const float*)d_in[17];
    float* out = (float*)d_out;

    float* wsf   = (float*)d_ws;
    float* stat1 = wsf;                 // 256
    float* stat2 = wsf + 256;           // 256
    float* SQe8  = wsf + 512;           // 8*256 = 2048  (per-XCD stat copies)
    float* act1  = wsf + 4096;          // 262144
    float* act2  = act1 + 262144;       // 262144
    short* hb    = (short*)(act2 + 262144);   // 131072 bf16
    short* Tbuf  = hb + 131072;               // 2048*8192 bf16 = 32 MB

    hipMemsetAsync(d_ws, 0, 4096 * sizeof(float), stream);

    k_l1<<<256, 256, 0, stream>>>(nf, W1, b1, act1, stat1);
    k_l2<<<256, 256, 0, stream>>>(act1, stat1, g1, be1, W2, b2, act2, stat2);
    k_l3b<<<256, 256, 0, stream>>>(act2, stat2, g2, be2, W3, b3, nf, W5, hb, Tbuf);

    edge_p1<<<4224, 256, 0, stream>>>(hb, Tbuf, b5, SQe8);
    edge_p2<<<4224, 256, 0, stream>>>(hb, Tbuf, b5, SQe8, W6, b6, g5, be5, out);
}